// Round 13
// baseline (154.275 us; speedup 1.0000x reference)
//
#include <hip/hip_runtime.h>
#include <hip/hip_bf16.h>

#define N_ROWS 131072
#define DIM 64
#define K_CODES 1024
#define NTILES 64
#define MARGIN 4e-5f
#define LIST_CAP 65536

typedef short short8 __attribute__((ext_vector_type(8)));
typedef float f32x4 __attribute__((ext_vector_type(4)));

__device__ __forceinline__ unsigned short f2bf(float f) {
    unsigned u = __float_as_uint(f);
    return (unsigned short)((u + 0x7fffu + ((u >> 16) & 1u)) >> 16);  // RNE
}
__device__ __forceinline__ float bf2f(unsigned short h) {
    return __uint_as_float(((unsigned)h) << 16);
}
__device__ __forceinline__ unsigned med3u(unsigned a, unsigned b, unsigned c) {
    unsigned d;
    asm("v_med3_u32 %0, %1, %2, %3" : "=v"(d) : "v"(a), "v"(b), "v"(c));
    return d;
}
__device__ __forceinline__ unsigned minu(unsigned a, unsigned b) { return a < b ? a : b; }
__device__ __forceinline__ unsigned maxu(unsigned a, unsigned b) { return a > b ? a : b; }

// monotone float->uint key (order-preserving, NaN-free inputs)
__device__ __forceinline__ unsigned f2key(float v) {
    unsigned u = __float_as_uint(v);
    return u ^ (unsigned)(((int)u >> 31) | 0x80000000);
}
// inverse (low bits already cleared/ignored by caller)
__device__ __forceinline__ float key2f(unsigned k) {
    unsigned kc = k & 0xFFFFFC00u;
    unsigned u = (kc & 0x80000000u) ? (kc ^ 0x80000000u) : ~kc;
    return __uint_as_float(u);
}

// np-exact squared-row-sum: elementwise square then pairwise 8-accumulator
__device__ __forceinline__ float np_sq64(const float* __restrict__ v) {
    float xx[DIM];
    #pragma unroll
    for (int d = 0; d < DIM; ++d) xx[d] = v[d] * v[d];
    float r[8];
    #pragma unroll
    for (int j = 0; j < 8; ++j) r[j] = xx[j];
    #pragma unroll
    for (int i = 8; i < DIM; i += 8)
        #pragma unroll
        for (int j = 0; j < 8; ++j) r[j] = r[j] + xx[i + j];
    return ((r[0]+r[1]) + (r[2]+r[3])) + ((r[4]+r[5]) + (r[6]+r[7]));
}

// np-exact einsum dot (verified R3 chain): 4 accs, 16-elem chunks, blocks 12,8,4,0
__device__ __forceinline__ float np_dot64(const float* __restrict__ xv,
                                          const float* __restrict__ ek) {
    float a0 = 0.f, a1 = 0.f, a2 = 0.f, a3 = 0.f;
    #pragma unroll
    for (int c = 0; c < DIM; c += 16)
        #pragma unroll
        for (int b = 12; b >= 0; b -= 4) {
            const int d = c + b;
            a0 = a0 + xv[d+0] * ek[d+0];
            a1 = a1 + xv[d+1] * ek[d+1];
            a2 = a2 + xv[d+2] * ek[d+2];
            a3 = a3 + xv[d+3] * ek[d+3];
        }
    return (a0 + a1) + (a2 + a3);
}

// ws: byte 0: cnt u32, byte 4: loss f32, float idx 4..1027: esq,
//     byte 8192: B panel 256KB, byte 270336: fixup list u32[65536]

__global__ void vq_prep(const float* __restrict__ emb, float* __restrict__ esq,
                        unsigned short* __restrict__ wsB,
                        unsigned int* __restrict__ cnt, float* __restrict__ loss) {
#pragma clang fp contract(off)
    const int t = blockIdx.x * blockDim.x + threadIdx.x;
    if (t == 0) { *cnt = 0u; *loss = 0.f; }
    const int k = t >> 2, c = t & 3;
    if (k >= K_CODES) return;
    const float* e = emb + (size_t)k * DIM;

    if (c == 0) esq[k] = np_sq64(e);

    const int off = (c & 1) * 32, sel = c >> 1;
    unsigned short val[32];
    #pragma unroll
    for (int j = 0; j < 32; ++j) {
        float v = e[off + j];
        unsigned short h = f2bf(v);
        val[j] = sel ? f2bf(v - bf2f(h)) : h;
    }
    const int tile = k >> 4, n = k & 15;
    #pragma unroll
    for (int g = 0; g < 4; ++g) {
        short8 s;
        #pragma unroll
        for (int j = 0; j < 8; ++j) s[j] = (short)val[g*8 + j];
        *reinterpret_cast<short8*>(wsB + ((size_t)((tile*4 + c)*64 + g*16 + n)) * 8) = s;
    }
}

__global__ __launch_bounds__(256, 2) void vq_mfma(const float* __restrict__ x,
        const float* __restrict__ emb, const float* __restrict__ esq,
        const unsigned short* __restrict__ wsB, float* __restrict__ out,
        unsigned int* __restrict__ cnt, unsigned int* __restrict__ list,
        float* __restrict__ loss) {
#pragma clang fp contract(off)
    const int tid = threadIdx.x;
    const int lane = tid & 63;
    const int w = tid >> 6;
    const int g = lane >> 4, res = lane & 15;
    const int rowbase = blockIdx.x * 128 + w * 32;   // 32 rows per wave (2 rgs)

    // A-frags: lane holds row (rowbase + rg*16 + res), k-slots g*8+j
    short8 Ah[2][2], Al[2][2];
    #pragma unroll
    for (int rg = 0; rg < 2; ++rg) {
        const float* xr = x + (size_t)(rowbase + rg*16 + res) * DIM;
        #pragma unroll
        for (int h = 0; h < 2; ++h) {
            float4 v0 = *reinterpret_cast<const float4*>(xr + h*32 + g*8);
            float4 v1 = *reinterpret_cast<const float4*>(xr + h*32 + g*8 + 4);
            float xv[8] = {v0.x, v0.y, v0.z, v0.w, v1.x, v1.y, v1.z, v1.w};
            short8 sh, sl;
            #pragma unroll
            for (int j = 0; j < 8; ++j) {
                unsigned short hb = f2bf(xv[j]);
                sh[j] = (short)hb;
                sl[j] = (short)f2bf(xv[j] - bf2f(hb));
            }
            Ah[rg][h] = sh; Al[rg][h] = sl;
        }
    }

    // packed top-3 per (row-slot): key = monotone(proxy) with idx in low 10 bits
    unsigned b1[8], b2[8], b3[8];
    #pragma unroll
    for (int s = 0; s < 8; ++s) { b1[s] = 0xFFFFFFFFu; b2[s] = 0xFFFFFFFFu; b3[s] = 0xFFFFFFFFu; }

    auto loadB = [&](short8* Bd, int ct) {
        const unsigned short* bp = wsB + ((size_t)(ct*4)*64 + lane) * 8;
        #pragma unroll
        for (int c = 0; c < 4; ++c)
            Bd[c] = *reinterpret_cast<const short8*>(bp + (size_t)c * 64 * 8);
    };

    auto compute = [&](int ct, const short8* B) {
        const float esqv = esq[ct*16 + res];
        const unsigned kcur = (unsigned)(ct*16 + res);
        #pragma unroll
        for (int rg = 0; rg < 2; ++rg) {
            f32x4 acc = {0.f, 0.f, 0.f, 0.f};
            acc = __builtin_amdgcn_mfma_f32_16x16x32_bf16(Ah[rg][0], B[0], acc, 0,0,0); // hh
            acc = __builtin_amdgcn_mfma_f32_16x16x32_bf16(Ah[rg][1], B[1], acc, 0,0,0);
            acc = __builtin_amdgcn_mfma_f32_16x16x32_bf16(Ah[rg][0], B[2], acc, 0,0,0); // hl
            acc = __builtin_amdgcn_mfma_f32_16x16x32_bf16(Ah[rg][1], B[3], acc, 0,0,0);
            acc = __builtin_amdgcn_mfma_f32_16x16x32_bf16(Al[rg][0], B[0], acc, 0,0,0); // lh
            acc = __builtin_amdgcn_mfma_f32_16x16x32_bf16(Al[rg][1], B[1], acc, 0,0,0);
            #pragma unroll
            for (int r = 0; r < 4; ++r) {
                float v = fmaf(-2.0f, acc[r], esqv);         // proxy = esq - 2*dot
                unsigned key = (f2key(v) & 0xFFFFFC00u) | kcur;
                const int s = rg*4 + r;
                unsigned o1 = b1[s], o2 = b2[s];
                b3[s] = med3u(key, o2, b3[s]);
                b2[s] = med3u(key, o1, o2);
                b1[s] = minu(o1, key);
            }
        }
    };

    short8 BA[4], BB[4];
    loadB(BA, 0);
    for (int ct = 0; ct < NTILES; ct += 2) {
        loadB(BB, ct + 1);
        compute(ct, BA);
        loadB(BA, (ct + 2) & 63);   // last iter reloads tile 0: unused
        compute(ct + 1, BB);
    }

    // top-3 merge across the 16 code-residue lanes (pure key math, indices free)
    #pragma unroll
    for (int m = 1; m < 16; m <<= 1) {
        #pragma unroll
        for (int s = 0; s < 8; ++s) {
            unsigned oa1 = __shfl_xor((int)b1[s], m, 64);
            unsigned oa2 = __shfl_xor((int)b2[s], m, 64);
            unsigned oa3 = __shfl_xor((int)b3[s], m, 64);
            unsigned m1 = minu(b1[s], oa1);
            unsigned m2 = minu(maxu(b1[s], oa1), minu(b2[s], oa2));
            unsigned m3 = minu(minu(maxu(b1[s], oa2), maxu(b2[s], oa1)),
                               minu(b3[s], oa3));
            b1[s] = m1; b2[s] = m2; b3[s] = m3;
        }
    }

    __shared__ unsigned s_k1[128], s_k2[128], s_k3[128];
    __shared__ int s_idx[128];
    if (res == 0) {
        #pragma unroll
        for (int s = 0; s < 8; ++s) {   // row_local = w*32 + rg*16 + g*4 + r
            const int rl = w*32 + (s >> 2)*16 + g*4 + (s & 3);
            s_k1[rl] = b1[s]; s_k2[rl] = b2[s]; s_k3[rl] = b3[s];
        }
    }
    __syncthreads();

    // resolve pass: 1 thread per row (tid<128). Common: outright winner.
    // Pair-tie: np-exact compare of the two candidates. Triple-tie: fixup.
    if (tid < 128) {
        const int row = blockIdx.x * 128 + tid;
        unsigned k1 = s_k1[tid], k2 = s_k2[tid], k3 = s_k3[tid];
        float f1 = key2f(k1), f2 = key2f(k2), f3 = key2f(k3);
        int idx;
        if (f3 - f1 < MARGIN) {
            unsigned slot = atomicAdd(cnt, 1u);
            if (slot < LIST_CAP) list[slot] = (unsigned)row;
            idx = -1;                              // fixup owns this row
        } else if (f2 - f1 < MARGIN) {
            const int ia = (int)(k1 & 0x3FFu), ib = (int)(k2 & 0x3FFu);
            float xv[DIM];
            const float4* xp = reinterpret_cast<const float4*>(x + (size_t)row * DIM);
            #pragma unroll
            for (int q = 0; q < 16; ++q) {
                float4 v = xp[q];
                xv[4*q+0] = v.x; xv[4*q+1] = v.y; xv[4*q+2] = v.z; xv[4*q+3] = v.w;
            }
            float xsq = np_sq64(xv);
            float ta = xsq + esq[ia];
            float da = ta - 2.0f * np_dot64(xv, emb + (size_t)ia * DIM);
            float tb = xsq + esq[ib];
            float db = tb - 2.0f * np_dot64(xv, emb + (size_t)ib * DIM);
            // np.argmin first-min semantics
            idx = (da < db) ? ia : ((db < da) ? ib : (ia < ib ? ia : ib));
        } else {
            idx = (int)(k1 & 0x3FFu);
        }
        s_idx[tid] = idx;
    }
    __syncthreads();

    // writeout: 2 threads per row (32 dims each)
    const int rl = tid >> 1, half = tid & 1;
    const int row = blockIdx.x * 128 + rl;
    const int idx = s_idx[rl];
    float lsum = 0.f;
    if (idx >= 0) {
        const float* xr = x + (size_t)row * DIM + half*32;
        const float* qr = emb + (size_t)idx * DIM + half*32;
        float* orow = out + (size_t)row * DIM + half*32;
        #pragma unroll
        for (int i = 0; i < 8; ++i) {
            float4 xv = reinterpret_cast<const float4*>(xr)[i];
            float4 qv = reinterpret_cast<const float4*>(qr)[i];
            float df0 = qv.x - xv.x, df1 = qv.y - xv.y;
            float df2 = qv.z - xv.z, df3 = qv.w - xv.w;
            lsum = fmaf(df0, df0, lsum); lsum = fmaf(df1, df1, lsum);
            lsum = fmaf(df2, df2, lsum); lsum = fmaf(df3, df3, lsum);
            float4 o = {xv.x + df0, xv.y + df1, xv.z + df2, xv.w + df3};
            reinterpret_cast<float4*>(orow)[i] = o;
        }
        if (half == 0) out[(size_t)N_ROWS * DIM + row] = (float)idx;
    }
    #pragma unroll
    for (int off = 32; off > 0; off >>= 1) lsum += __shfl_down(lsum, off, 64);
    if (lane == 0) atomicAdd(loss, lsum);
}

// full np-exact rescan, only for triple-tie rows (rare)
__global__ void vq_fixup(const float* __restrict__ x, const float* __restrict__ emb,
                         const float* __restrict__ esq,
                         const unsigned int* __restrict__ cnt,
                         const unsigned int* __restrict__ list,
                         float* __restrict__ out, float* __restrict__ loss) {
#pragma clang fp contract(off)
    const int lane = threadIdx.x & 63;
    const int wid = (blockIdx.x * blockDim.x + threadIdx.x) >> 6;
    const int nw = (256 * 256) >> 6;
    unsigned count = *cnt;
    if (count > LIST_CAP) count = LIST_CAP;
    for (unsigned i = wid; i < count; i += nw) {
        const int row = (int)list[i];
        float xv[DIM];
        const float4* xp = reinterpret_cast<const float4*>(x + (size_t)row * DIM);
        #pragma unroll
        for (int q = 0; q < 16; ++q) {
            float4 v = xp[q];
            xv[4*q+0] = v.x; xv[4*q+1] = v.y; xv[4*q+2] = v.z; xv[4*q+3] = v.w;
        }
        float xsq = np_sq64(xv);
        float best = INFINITY; int bidx = 0x7fffffff;
        for (int t = 0; t < K_CODES / 64; ++t) {
            const int k = lane + t * 64;   // ascending per lane
            float dot = np_dot64(xv, emb + (size_t)k * DIM);
            float tt = xsq + esq[k];
            float dist = tt - 2.0f * dot;
            if (dist < best) { best = dist; bidx = k; }
        }
        #pragma unroll
        for (int m = 1; m < 64; m <<= 1) {   // lexicographic (dist, idx) min
            float ob = __shfl_xor(best, m, 64);
            int   oi = __shfl_xor(bidx, m, 64);
            if (ob < best || (ob == best && oi < bidx)) { best = ob; bidx = oi; }
        }
        const float xd = x[(size_t)row * DIM + lane];
        const float qd = emb[(size_t)bidx * DIM + lane];
        const float df = qd - xd;
        out[(size_t)row * DIM + lane] = xd + df;
        if (lane == 0) out[(size_t)N_ROWS * DIM + row] = (float)bidx;
        float l2 = df * df;
        #pragma unroll
        for (int off = 32; off > 0; off >>= 1) l2 += __shfl_down(l2, off, 64);
        if (lane == 0) atomicAdd(loss, l2);
    }
}

__global__ void vq_final(const float* __restrict__ loss_acc, float* __restrict__ out_loss) {
    if (threadIdx.x == 0 && blockIdx.x == 0)
        out_loss[0] = loss_acc[0] / (float)((size_t)N_ROWS * DIM);
}

extern "C" void kernel_launch(void* const* d_in, const int* in_sizes, int n_in,
                              void* d_out, int out_size, void* d_ws, size_t ws_size,
                              hipStream_t stream) {
    const float* x   = (const float*)d_in[0];
    const float* emb = (const float*)d_in[1];
    float* out = (float*)d_out;

    unsigned int* cnt  = (unsigned int*)d_ws;
    float* loss        = (float*)d_ws + 1;
    float* esq         = (float*)d_ws + 4;
    unsigned short* wsB = (unsigned short*)((char*)d_ws + 8192);
    unsigned int* list = (unsigned int*)((char*)d_ws + 270336);

    vq_prep<<<dim3(16), dim3(256), 0, stream>>>(emb, esq, wsB, cnt, loss);
    vq_mfma<<<dim3(N_ROWS / 128), dim3(256), 0, stream>>>(x, emb, esq, wsB, out,
                                                          cnt, list, loss);
    vq_fixup<<<dim3(256), dim3(256), 0, stream>>>(x, emb, esq, cnt, list, out, loss);
    vq_final<<<dim3(1), dim3(1), 0, stream>>>(loss, out + (size_t)N_ROWS * DIM + N_ROWS);
}

// Round 14
// 144.666 us; speedup vs baseline: 1.0664x; 1.0664x over previous
//
#include <hip/hip_runtime.h>
#include <hip/hip_bf16.h>

#define N_ROWS 131072
#define DIM 64
#define K_CODES 1024
#define NTILES 64
#define MARGIN 4e-5f
#define LIST_CAP 65536

typedef short short8 __attribute__((ext_vector_type(8)));
typedef float f32x4 __attribute__((ext_vector_type(4)));

__device__ __forceinline__ unsigned short f2bf(float f) {
    unsigned u = __float_as_uint(f);
    return (unsigned short)((u + 0x7fffu + ((u >> 16) & 1u)) >> 16);  // RNE
}
__device__ __forceinline__ float bf2f(unsigned short h) {
    return __uint_as_float(((unsigned)h) << 16);
}
__device__ __forceinline__ unsigned med3u(unsigned a, unsigned b, unsigned c) {
    unsigned d;
    asm("v_med3_u32 %0, %1, %2, %3" : "=v"(d) : "v"(a), "v"(b), "v"(c));
    return d;
}
__device__ __forceinline__ unsigned minu(unsigned a, unsigned b) { return a < b ? a : b; }
__device__ __forceinline__ unsigned maxu(unsigned a, unsigned b) { return a > b ? a : b; }

// monotone float->uint key (order-preserving, NaN-free inputs)
__device__ __forceinline__ unsigned f2key(float v) {
    unsigned u = __float_as_uint(v);
    return u ^ (unsigned)(((int)u >> 31) | 0x80000000);
}
// inverse (low bits already cleared/ignored by caller)
__device__ __forceinline__ float key2f(unsigned k) {
    unsigned kc = k & 0xFFFFFC00u;
    unsigned u = (kc & 0x80000000u) ? (kc ^ 0x80000000u) : ~kc;
    return __uint_as_float(u);
}

// np-exact squared-row-sum: elementwise square then pairwise 8-accumulator
__device__ __forceinline__ float np_sq64(const float* __restrict__ v) {
    float xx[DIM];
    #pragma unroll
    for (int d = 0; d < DIM; ++d) xx[d] = v[d] * v[d];
    float r[8];
    #pragma unroll
    for (int j = 0; j < 8; ++j) r[j] = xx[j];
    #pragma unroll
    for (int i = 8; i < DIM; i += 8)
        #pragma unroll
        for (int j = 0; j < 8; ++j) r[j] = r[j] + xx[i + j];
    return ((r[0]+r[1]) + (r[2]+r[3])) + ((r[4]+r[5]) + (r[6]+r[7]));
}

// np-exact einsum dot (verified R3 chain): 4 accs, 16-elem chunks, blocks 12,8,4,0
__device__ __forceinline__ float np_dot64(const float* __restrict__ xv,
                                          const float* __restrict__ ek) {
    float a0 = 0.f, a1 = 0.f, a2 = 0.f, a3 = 0.f;
    #pragma unroll
    for (int c = 0; c < DIM; c += 16)
        #pragma unroll
        for (int b = 12; b >= 0; b -= 4) {
            const int d = c + b;
            a0 = a0 + xv[d+0] * ek[d+0];
            a1 = a1 + xv[d+1] * ek[d+1];
            a2 = a2 + xv[d+2] * ek[d+2];
            a3 = a3 + xv[d+3] * ek[d+3];
        }
    return (a0 + a1) + (a2 + a3);
}

// ws: byte 0: cnt u32, byte 4: loss f32, float idx 4..1027: esq,
//     byte 8192: B panel 256KB, byte 270336: fixup list u32[65536]

__global__ void vq_prep(const float* __restrict__ emb, float* __restrict__ esq,
                        unsigned short* __restrict__ wsB,
                        unsigned int* __restrict__ cnt, float* __restrict__ loss) {
#pragma clang fp contract(off)
    const int t = blockIdx.x * blockDim.x + threadIdx.x;
    if (t == 0) { *cnt = 0u; *loss = 0.f; }
    const int k = t >> 2, c = t & 3;
    if (k >= K_CODES) return;
    const float* e = emb + (size_t)k * DIM;

    if (c == 0) esq[k] = np_sq64(e);

    const int off = (c & 1) * 32, sel = c >> 1;
    unsigned short val[32];
    #pragma unroll
    for (int j = 0; j < 32; ++j) {
        float v = e[off + j];
        unsigned short h = f2bf(v);
        val[j] = sel ? f2bf(v - bf2f(h)) : h;
    }
    const int tile = k >> 4, n = k & 15;
    #pragma unroll
    for (int g = 0; g < 4; ++g) {
        short8 s;
        #pragma unroll
        for (int j = 0; j < 8; ++j) s[j] = (short)val[g*8 + j];
        *reinterpret_cast<short8*>(wsB + ((size_t)((tile*4 + c)*64 + g*16 + n)) * 8) = s;
    }
}

__global__ __launch_bounds__(256, 2) void vq_mfma(const float* __restrict__ x,
        const float* __restrict__ emb, const float* __restrict__ esq,
        const unsigned short* __restrict__ wsB, float* __restrict__ out,
        unsigned int* __restrict__ cnt, unsigned int* __restrict__ list,
        float* __restrict__ loss) {
#pragma clang fp contract(off)
    const int tid = threadIdx.x;
    const int lane = tid & 63;
    const int w = tid >> 6;
    const int g = lane >> 4, res = lane & 15;
    const int rowbase = blockIdx.x * 256 + w * 64;   // 64 rows per wave (4 rgs)

    // A-frags: lane holds row (rowbase + rg*16 + res), k-slots g*8+j
    short8 Ah[4][2], Al[4][2];
    #pragma unroll
    for (int rg = 0; rg < 4; ++rg) {
        const float* xr = x + (size_t)(rowbase + rg*16 + res) * DIM;
        #pragma unroll
        for (int h = 0; h < 2; ++h) {
            float4 v0 = *reinterpret_cast<const float4*>(xr + h*32 + g*8);
            float4 v1 = *reinterpret_cast<const float4*>(xr + h*32 + g*8 + 4);
            float xv[8] = {v0.x, v0.y, v0.z, v0.w, v1.x, v1.y, v1.z, v1.w};
            short8 sh, sl;
            #pragma unroll
            for (int j = 0; j < 8; ++j) {
                unsigned short hb = f2bf(xv[j]);
                sh[j] = (short)hb;
                sl[j] = (short)f2bf(xv[j] - bf2f(hb));
            }
            Ah[rg][h] = sh; Al[rg][h] = sl;
        }
    }

    // packed top-3 per (row-slot): key = monotone(proxy) with idx in low 10 bits
    unsigned b1[16], b2[16], b3[16];
    #pragma unroll
    for (int s = 0; s < 16; ++s) { b1[s] = 0xFFFFFFFFu; b2[s] = 0xFFFFFFFFu; b3[s] = 0xFFFFFFFFu; }

    auto loadB = [&](short8* Bd, int ct) {
        const unsigned short* bp = wsB + ((size_t)(ct*4)*64 + lane) * 8;
        #pragma unroll
        for (int c = 0; c < 4; ++c)
            Bd[c] = *reinterpret_cast<const short8*>(bp + (size_t)c * 64 * 8);
    };

    // j-outer / rg-inner: 4 independent MFMA chains round-robin, so the matrix
    // pipe never waits on a single chain's latency; ALL key updates deferred
    // to one tail burst (no acc-read between chains -> no in-order stall).
    // Per-acc op order unchanged vs R12: hh0,hh1,hl0,hl1,lh0,lh1 (bit-identical).
    auto compute = [&](int ct, const short8* B, float esqv) {
        const unsigned kcur = (unsigned)(ct*16 + res);
        f32x4 acc[4];
        #pragma unroll
        for (int rg = 0; rg < 4; ++rg) acc[rg] = f32x4{0.f, 0.f, 0.f, 0.f};
        #pragma unroll
        for (int rg = 0; rg < 4; ++rg)
            acc[rg] = __builtin_amdgcn_mfma_f32_16x16x32_bf16(Ah[rg][0], B[0], acc[rg], 0,0,0);
        #pragma unroll
        for (int rg = 0; rg < 4; ++rg)
            acc[rg] = __builtin_amdgcn_mfma_f32_16x16x32_bf16(Ah[rg][1], B[1], acc[rg], 0,0,0);
        #pragma unroll
        for (int rg = 0; rg < 4; ++rg)
            acc[rg] = __builtin_amdgcn_mfma_f32_16x16x32_bf16(Ah[rg][0], B[2], acc[rg], 0,0,0);
        #pragma unroll
        for (int rg = 0; rg < 4; ++rg)
            acc[rg] = __builtin_amdgcn_mfma_f32_16x16x32_bf16(Ah[rg][1], B[3], acc[rg], 0,0,0);
        #pragma unroll
        for (int rg = 0; rg < 4; ++rg)
            acc[rg] = __builtin_amdgcn_mfma_f32_16x16x32_bf16(Al[rg][0], B[0], acc[rg], 0,0,0);
        #pragma unroll
        for (int rg = 0; rg < 4; ++rg)
            acc[rg] = __builtin_amdgcn_mfma_f32_16x16x32_bf16(Al[rg][1], B[1], acc[rg], 0,0,0);
        // tail burst: 16 key updates (only acc-consumers in this tile)
        #pragma unroll
        for (int rg = 0; rg < 4; ++rg) {
            #pragma unroll
            for (int r = 0; r < 4; ++r) {
                float v = fmaf(-2.0f, acc[rg][r], esqv);     // proxy = esq - 2*dot
                unsigned key = (f2key(v) & 0xFFFFFC00u) | kcur;
                const int s = rg*4 + r;
                unsigned o1 = b1[s], o2 = b2[s];
                b3[s] = med3u(key, o2, b3[s]);
                b2[s] = med3u(key, o1, o2);
                b1[s] = minu(o1, key);
            }
        }
    };

    short8 BA[4], BB[4];
    loadB(BA, 0);
    for (int ct = 0; ct < NTILES; ct += 2) {
        // prefetch esq for both tiles of this pair up front
        float esqA = esq[ct*16 + res];
        float esqB = esq[(ct + 1)*16 + res];
        loadB(BB, ct + 1);
        compute(ct, BA, esqA);
        loadB(BA, (ct + 2) & 63);   // last iter reloads tile 0: unused
        compute(ct + 1, BB, esqB);
    }

    // top-3 merge across the 16 code-residue lanes (pure key math, indices free)
    #pragma unroll
    for (int m = 1; m < 16; m <<= 1) {
        #pragma unroll
        for (int s = 0; s < 16; ++s) {
            unsigned oa1 = __shfl_xor((int)b1[s], m, 64);
            unsigned oa2 = __shfl_xor((int)b2[s], m, 64);
            unsigned oa3 = __shfl_xor((int)b3[s], m, 64);
            unsigned m1 = minu(b1[s], oa1);
            unsigned m2 = minu(maxu(b1[s], oa1), minu(b2[s], oa2));
            unsigned m3 = minu(minu(maxu(b1[s], oa2), maxu(b2[s], oa1)),
                               minu(b3[s], oa3));
            b1[s] = m1; b2[s] = m2; b3[s] = m3;
        }
    }

    __shared__ unsigned s_k1[256], s_k2[256], s_k3[256];
    __shared__ int s_idx[256];
    if (res == 0) {
        #pragma unroll
        for (int s = 0; s < 16; ++s) {   // row_local = w*64 + rg*16 + g*4 + r
            const int rl = w*64 + (s >> 2)*16 + g*4 + (s & 3);
            s_k1[rl] = b1[s]; s_k2[rl] = b2[s]; s_k3[rl] = b3[s];
        }
    }
    __syncthreads();

    // resolve pass: 1 thread per row. Common: outright winner. Pair-tie:
    // np-exact compare of the two candidates. Triple-tie: defer to fixup.
    {
        const int row = blockIdx.x * 256 + tid;
        unsigned k1 = s_k1[tid], k2 = s_k2[tid], k3 = s_k3[tid];
        float f1 = key2f(k1), f2 = key2f(k2), f3 = key2f(k3);
        int idx;
        if (f3 - f1 < MARGIN) {
            unsigned slot = atomicAdd(cnt, 1u);
            if (slot < LIST_CAP) list[slot] = (unsigned)row;
            idx = -1;                              // fixup owns this row
        } else if (f2 - f1 < MARGIN) {
            const int ia = (int)(k1 & 0x3FFu), ib = (int)(k2 & 0x3FFu);
            float xv[DIM];
            const float4* xp = reinterpret_cast<const float4*>(x + (size_t)row * DIM);
            #pragma unroll
            for (int q = 0; q < 16; ++q) {
                float4 v = xp[q];
                xv[4*q+0] = v.x; xv[4*q+1] = v.y; xv[4*q+2] = v.z; xv[4*q+3] = v.w;
            }
            float xsq = np_sq64(xv);
            float ta = xsq + esq[ia];
            float da = ta - 2.0f * np_dot64(xv, emb + (size_t)ia * DIM);
            float tb = xsq + esq[ib];
            float db = tb - 2.0f * np_dot64(xv, emb + (size_t)ib * DIM);
            // np.argmin first-min semantics
            idx = (da < db) ? ia : ((db < da) ? ib : (ia < ib ? ia : ib));
        } else {
            idx = (int)(k1 & 0x3FFu);
        }
        s_idx[tid] = idx;
    }
    __syncthreads();

    // writeout: 1 thread per row (64 dims)
    const int row = blockIdx.x * 256 + tid;
    const int idx = s_idx[tid];
    float lsum = 0.f;
    if (idx >= 0) {
        const float* xr = x + (size_t)row * DIM;
        const float* qr = emb + (size_t)idx * DIM;
        float* orow = out + (size_t)row * DIM;
        #pragma unroll
        for (int i = 0; i < 16; ++i) {
            float4 xv = reinterpret_cast<const float4*>(xr)[i];
            float4 qv = reinterpret_cast<const float4*>(qr)[i];
            float df0 = qv.x - xv.x, df1 = qv.y - xv.y;
            float df2 = qv.z - xv.z, df3 = qv.w - xv.w;
            lsum = fmaf(df0, df0, lsum); lsum = fmaf(df1, df1, lsum);
            lsum = fmaf(df2, df2, lsum); lsum = fmaf(df3, df3, lsum);
            float4 o = {xv.x + df0, xv.y + df1, xv.z + df2, xv.w + df3};
            reinterpret_cast<float4*>(orow)[i] = o;
        }
        out[(size_t)N_ROWS * DIM + row] = (float)idx;
    }
    #pragma unroll
    for (int off = 32; off > 0; off >>= 1) lsum += __shfl_down(lsum, off, 64);
    if (lane == 0) atomicAdd(loss, lsum);
}

// full np-exact rescan, only for triple-tie rows (rare)
__global__ void vq_fixup(const float* __restrict__ x, const float* __restrict__ emb,
                         const float* __restrict__ esq,
                         const unsigned int* __restrict__ cnt,
                         const unsigned int* __restrict__ list,
                         float* __restrict__ out, float* __restrict__ loss) {
#pragma clang fp contract(off)
    const int lane = threadIdx.x & 63;
    const int wid = (blockIdx.x * blockDim.x + threadIdx.x) >> 6;
    const int nw = (256 * 256) >> 6;
    unsigned count = *cnt;
    if (count > LIST_CAP) count = LIST_CAP;
    for (unsigned i = wid; i < count; i += nw) {
        const int row = (int)list[i];
        float xv[DIM];
        const float4* xp = reinterpret_cast<const float4*>(x + (size_t)row * DIM);
        #pragma unroll
        for (int q = 0; q < 16; ++q) {
            float4 v = xp[q];
            xv[4*q+0] = v.x; xv[4*q+1] = v.y; xv[4*q+2] = v.z; xv[4*q+3] = v.w;
        }
        float xsq = np_sq64(xv);
        float best = INFINITY; int bidx = 0x7fffffff;
        for (int t = 0; t < K_CODES / 64; ++t) {
            const int k = lane + t * 64;   // ascending per lane
            float dot = np_dot64(xv, emb + (size_t)k * DIM);
            float tt = xsq + esq[k];
            float dist = tt - 2.0f * dot;
            if (dist < best) { best = dist; bidx = k; }
        }
        #pragma unroll
        for (int m = 1; m < 64; m <<= 1) {   // lexicographic (dist, idx) min
            float ob = __shfl_xor(best, m, 64);
            int   oi = __shfl_xor(bidx, m, 64);
            if (ob < best || (ob == best && oi < bidx)) { best = ob; bidx = oi; }
        }
        const float xd = x[(size_t)row * DIM + lane];
        const float qd = emb[(size_t)bidx * DIM + lane];
        const float df = qd - xd;
        out[(size_t)row * DIM + lane] = xd + df;
        if (lane == 0) out[(size_t)N_ROWS * DIM + row] = (float)bidx;
        float l2 = df * df;
        #pragma unroll
        for (int off = 32; off > 0; off >>= 1) l2 += __shfl_down(l2, off, 64);
        if (lane == 0) atomicAdd(loss, l2);
    }
}

__global__ void vq_final(const float* __restrict__ loss_acc, float* __restrict__ out_loss) {
    if (threadIdx.x == 0 && blockIdx.x == 0)
        out_loss[0] = loss_acc[0] / (float)((size_t)N_ROWS * DIM);
}

extern "C" void kernel_launch(void* const* d_in, const int* in_sizes, int n_in,
                              void* d_out, int out_size, void* d_ws, size_t ws_size,
                              hipStream_t stream) {
    const float* x   = (const float*)d_in[0];
    const float* emb = (const float*)d_in[1];
    float* out = (float*)d_out;

    unsigned int* cnt  = (unsigned int*)d_ws;
    float* loss        = (float*)d_ws + 1;
    float* esq         = (float*)d_ws + 4;
    unsigned short* wsB = (unsigned short*)((char*)d_ws + 8192);
    unsigned int* list = (unsigned int*)((char*)d_ws + 270336);

    vq_prep<<<dim3(16), dim3(256), 0, stream>>>(emb, esq, wsB, cnt, loss);
    vq_mfma<<<dim3(N_ROWS / 256), dim3(256), 0, stream>>>(x, emb, esq, wsB, out,
                                                          cnt, list, loss);
    vq_fixup<<<dim3(256), dim3(256), 0, stream>>>(x, emb, esq, cnt, list, out, loss);
    vq_final<<<dim3(1), dim3(1), 0, stream>>>(loss, out + (size_t)N_ROWS * DIM + N_ROWS);
}

// Round 15
// 134.474 us; speedup vs baseline: 1.1473x; 1.0758x over previous
//
#include <hip/hip_runtime.h>
#include <hip/hip_bf16.h>

#define N_ROWS 131072
#define DIM 64
#define K_CODES 1024
#define NTILES 64
#define MARGIN 4e-5f
#define LIST_CAP 65536

typedef short short8 __attribute__((ext_vector_type(8)));
typedef float f32x4 __attribute__((ext_vector_type(4)));

__device__ __forceinline__ unsigned short f2bf(float f) {
    unsigned u = __float_as_uint(f);
    return (unsigned short)((u + 0x7fffu + ((u >> 16) & 1u)) >> 16);  // RNE
}
__device__ __forceinline__ float bf2f(unsigned short h) {
    return __uint_as_float(((unsigned)h) << 16);
}

// np-exact squared-row-sum: elementwise square then pairwise 8-accumulator
__device__ __forceinline__ float np_sq64(const float* __restrict__ v) {
    float xx[DIM];
    #pragma unroll
    for (int d = 0; d < DIM; ++d) xx[d] = v[d] * v[d];
    float r[8];
    #pragma unroll
    for (int j = 0; j < 8; ++j) r[j] = xx[j];
    #pragma unroll
    for (int i = 8; i < DIM; i += 8)
        #pragma unroll
        for (int j = 0; j < 8; ++j) r[j] = r[j] + xx[i + j];
    return ((r[0]+r[1]) + (r[2]+r[3])) + ((r[4]+r[5]) + (r[6]+r[7]));
}

// np-exact einsum dot (verified R3 chain): 4 accs, 16-elem chunks, blocks 12,8,4,0
__device__ __forceinline__ float np_dot64(const float* __restrict__ xv,
                                          const float* __restrict__ ek) {
    float a0 = 0.f, a1 = 0.f, a2 = 0.f, a3 = 0.f;
    #pragma unroll
    for (int c = 0; c < DIM; c += 16)
        #pragma unroll
        for (int b = 12; b >= 0; b -= 4) {
            const int d = c + b;
            a0 = a0 + xv[d+0] * ek[d+0];
            a1 = a1 + xv[d+1] * ek[d+1];
            a2 = a2 + xv[d+2] * ek[d+2];
            a3 = a3 + xv[d+3] * ek[d+3];
        }
    return (a0 + a1) + (a2 + a3);
}

// ws: byte 0: cnt u32, byte 4: loss f32, float idx 4..1027: esq,
//     byte 8192: B panel 256KB, byte 270336: fixup list u32[65536]

__global__ void vq_prep(const float* __restrict__ emb, float* __restrict__ esq,
                        unsigned short* __restrict__ wsB,
                        unsigned int* __restrict__ cnt, float* __restrict__ loss) {
#pragma clang fp contract(off)
    const int t = blockIdx.x * blockDim.x + threadIdx.x;
    if (t == 0) { *cnt = 0u; *loss = 0.f; }
    const int k = t >> 2, c = t & 3;
    if (k >= K_CODES) return;
    const float* e = emb + (size_t)k * DIM;

    if (c == 0) esq[k] = np_sq64(e);

    const int off = (c & 1) * 32, sel = c >> 1;
    unsigned short val[32];
    #pragma unroll
    for (int j = 0; j < 32; ++j) {
        float v = e[off + j];
        unsigned short h = f2bf(v);
        val[j] = sel ? f2bf(v - bf2f(h)) : h;
    }
    const int tile = k >> 4, n = k & 15;
    #pragma unroll
    for (int g = 0; g < 4; ++g) {
        short8 s;
        #pragma unroll
        for (int j = 0; j < 8; ++j) s[j] = (short)val[g*8 + j];
        *reinterpret_cast<short8*>(wsB + ((size_t)((tile*4 + c)*64 + g*16 + n)) * 8) = s;
    }
}

__global__ __launch_bounds__(256, 2) void vq_mfma(const float* __restrict__ x,
        const float* __restrict__ emb, const float* __restrict__ esq,
        const unsigned short* __restrict__ wsB, float* __restrict__ out,
        unsigned int* __restrict__ cnt, unsigned int* __restrict__ list,
        float* __restrict__ loss) {
#pragma clang fp contract(off)
    const int tid = threadIdx.x;
    const int lane = tid & 63;
    const int w = tid >> 6;
    const int g = lane >> 4, res = lane & 15;
    const int rowbase = blockIdx.x * 256 + w * 64;   // 64 rows per wave (4 rgs)

    // A-frags: lane holds row (rowbase + rg*16 + res), k-slots g*8+j
    short8 Ah[4][2], Al[4][2];
    #pragma unroll
    for (int rg = 0; rg < 4; ++rg) {
        const float* xr = x + (size_t)(rowbase + rg*16 + res) * DIM;
        #pragma unroll
        for (int h = 0; h < 2; ++h) {
            float4 v0 = *reinterpret_cast<const float4*>(xr + h*32 + g*8);
            float4 v1 = *reinterpret_cast<const float4*>(xr + h*32 + g*8 + 4);
            float xv[8] = {v0.x, v0.y, v0.z, v0.w, v1.x, v1.y, v1.z, v1.w};
            short8 sh, sl;
            #pragma unroll
            for (int j = 0; j < 8; ++j) {
                unsigned short hb = f2bf(xv[j]);
                sh[j] = (short)hb;
                sl[j] = (short)f2bf(xv[j] - bf2f(hb));
            }
            Ah[rg][h] = sh; Al[rg][h] = sl;
        }
    }

    // float-key top-3 per row-slot: key = proxy with idx injected in the low
    // 10 mantissa bits (one v_and_or_b32). Quantization ~1024 ulp of |proxy|
    // near the min (~1e-6) is absorbed by MARGIN; tie-direction quirks are
    // always margin-flagged -> exact resolve/fixup covers them.
    float b1[16], b2[16], b3[16];
    const float FINF = __uint_as_float(0x7F800000u);
    #pragma unroll
    for (int s = 0; s < 16; ++s) { b1[s] = FINF; b2[s] = FINF; b3[s] = FINF; }

    auto loadB = [&](short8* Bd, int ct) {
        const unsigned short* bp = wsB + ((size_t)(ct*4)*64 + lane) * 8;
        #pragma unroll
        for (int c = 0; c < 4; ++c)
            Bd[c] = *reinterpret_cast<const short8*>(bp + (size_t)c * 64 * 8);
    };

    // 24 MFMAs, j-outer / rg-inner (4 independent chains round-robin)
    auto MF = [&](f32x4* acc, const short8* B) {
        #pragma unroll
        for (int rg = 0; rg < 4; ++rg) acc[rg] = f32x4{0.f, 0.f, 0.f, 0.f};
        #pragma unroll
        for (int rg = 0; rg < 4; ++rg)
            acc[rg] = __builtin_amdgcn_mfma_f32_16x16x32_bf16(Ah[rg][0], B[0], acc[rg], 0,0,0);
        #pragma unroll
        for (int rg = 0; rg < 4; ++rg)
            acc[rg] = __builtin_amdgcn_mfma_f32_16x16x32_bf16(Ah[rg][1], B[1], acc[rg], 0,0,0);
        #pragma unroll
        for (int rg = 0; rg < 4; ++rg)
            acc[rg] = __builtin_amdgcn_mfma_f32_16x16x32_bf16(Ah[rg][0], B[2], acc[rg], 0,0,0);
        #pragma unroll
        for (int rg = 0; rg < 4; ++rg)
            acc[rg] = __builtin_amdgcn_mfma_f32_16x16x32_bf16(Ah[rg][1], B[3], acc[rg], 0,0,0);
        #pragma unroll
        for (int rg = 0; rg < 4; ++rg)
            acc[rg] = __builtin_amdgcn_mfma_f32_16x16x32_bf16(Al[rg][0], B[0], acc[rg], 0,0,0);
        #pragma unroll
        for (int rg = 0; rg < 4; ++rg)
            acc[rg] = __builtin_amdgcn_mfma_f32_16x16x32_bf16(Al[rg][1], B[1], acc[rg], 0,0,0);
    };

    // 16 key updates: fmaf + and_or(inject idx) + med3f + med3f + minf
    auto KY = [&](const f32x4* acc, float esqv, int ct) {
        const unsigned kcur = (unsigned)(ct*16 + res);
        #pragma unroll
        for (int rg = 0; rg < 4; ++rg) {
            #pragma unroll
            for (int r = 0; r < 4; ++r) {
                float v = fmaf(-2.0f, acc[rg][r], esqv);   // proxy = esq - 2*dot
                float key = __uint_as_float((__float_as_uint(v) & 0xFFFFFC00u) | kcur);
                const int s = rg*4 + r;
                float o1 = b1[s], o2 = b2[s];
                b3[s] = __builtin_amdgcn_fmed3f(key, o2, b3[s]);
                b2[s] = __builtin_amdgcn_fmed3f(key, o1, o2);
                b1[s] = fminf(o1, key);
            }
        }
    };

    // software pipeline: loadB(2 ahead) -> MF(other tile) -> KY(prev tile)
    short8 B0[4], B1[4];
    f32x4 accA[4], accB[4];
    float e0, e1;

    loadB(B0, 0); e0 = esq[res];
    loadB(B1, 1); e1 = esq[16 + res];
    MF(accA, B0);                       // tile 0
    for (int p = 0; p < 31; ++p) {      // tiles 2p+1, 2p+2
        loadB(B0, 2*p + 2);
        MF(accB, B1);                   // tile 2p+1 (covers B0 latency)
        KY(accA, e0, 2*p);              // keys tile 2p under accB's MFMA time
        e0 = esq[(2*p + 2)*16 + res];
        loadB(B1, 2*p + 3);
        MF(accA, B0);                   // tile 2p+2
        KY(accB, e1, 2*p + 1);
        e1 = esq[(2*p + 3)*16 + res];
    }
    MF(accB, B1);                       // tile 63
    KY(accA, e0, 62);
    KY(accB, e1, 63);

    // top-3 merge across the 16 code-residue lanes (float order-stat network)
    #pragma unroll
    for (int m = 1; m < 16; m <<= 1) {
        #pragma unroll
        for (int s = 0; s < 16; ++s) {
            float oa1 = __shfl_xor(b1[s], m, 64);
            float oa2 = __shfl_xor(b2[s], m, 64);
            float oa3 = __shfl_xor(b3[s], m, 64);
            float m1 = fminf(b1[s], oa1);
            float m2 = fminf(fmaxf(b1[s], oa1), fminf(b2[s], oa2));
            float m3 = fminf(fminf(fmaxf(b1[s], oa2), fmaxf(b2[s], oa1)),
                             fminf(b3[s], oa3));
            b1[s] = m1; b2[s] = m2; b3[s] = m3;
        }
    }

    __shared__ float s_k1[256], s_k2[256], s_k3[256];
    __shared__ int s_idx[256];
    if (res == 0) {
        #pragma unroll
        for (int s = 0; s < 16; ++s) {   // row_local = w*64 + rg*16 + g*4 + r
            const int rl = w*64 + (s >> 2)*16 + g*4 + (s & 3);
            s_k1[rl] = b1[s]; s_k2[rl] = b2[s]; s_k3[rl] = b3[s];
        }
    }
    __syncthreads();

    // resolve pass: 1 thread per row. Common: outright winner. Pair-tie:
    // np-exact compare of the two candidates. Triple-tie: defer to fixup.
    {
        const int row = blockIdx.x * 256 + tid;
        unsigned u1 = __float_as_uint(s_k1[tid]);
        unsigned u2 = __float_as_uint(s_k2[tid]);
        unsigned u3 = __float_as_uint(s_k3[tid]);
        float f1 = __uint_as_float(u1 & 0xFFFFFC00u);
        float f2 = __uint_as_float(u2 & 0xFFFFFC00u);
        float f3 = __uint_as_float(u3 & 0xFFFFFC00u);
        int idx;
        if (f3 - f1 < MARGIN) {
            unsigned slot = atomicAdd(cnt, 1u);
            if (slot < LIST_CAP) list[slot] = (unsigned)row;
            idx = -1;                              // fixup owns this row
        } else if (f2 - f1 < MARGIN) {
            const int ia = (int)(u1 & 0x3FFu), ib = (int)(u2 & 0x3FFu);
            float xv[DIM];
            const float4* xp = reinterpret_cast<const float4*>(x + (size_t)row * DIM);
            #pragma unroll
            for (int q = 0; q < 16; ++q) {
                float4 v = xp[q];
                xv[4*q+0] = v.x; xv[4*q+1] = v.y; xv[4*q+2] = v.z; xv[4*q+3] = v.w;
            }
            float xsq = np_sq64(xv);
            float ta = xsq + esq[ia];
            float da = ta - 2.0f * np_dot64(xv, emb + (size_t)ia * DIM);
            float tb = xsq + esq[ib];
            float db = tb - 2.0f * np_dot64(xv, emb + (size_t)ib * DIM);
            // np.argmin first-min semantics
            idx = (da < db) ? ia : ((db < da) ? ib : (ia < ib ? ia : ib));
        } else {
            idx = (int)(u1 & 0x3FFu);
        }
        s_idx[tid] = idx;
    }
    __syncthreads();

    // writeout: 2 threads per row (32 dims each), 2 passes of 128 rows.
    // 128B-stride halves coalesce cleanly (R13: WRITE_SIZE == ideal 33 MB;
    // 1-thread/row 256B-stride measured ~62 MB write amplification).
    float lsum = 0.f;
    #pragma unroll
    for (int pass = 0; pass < 2; ++pass) {
        const int rl = (tid >> 1) + pass * 128, half = tid & 1;
        const int row = blockIdx.x * 256 + rl;
        const int idx = s_idx[rl];
        if (idx >= 0) {
            const float* xr = x + (size_t)row * DIM + half*32;
            const float* qr = emb + (size_t)idx * DIM + half*32;
            float* orow = out + (size_t)row * DIM + half*32;
            #pragma unroll
            for (int i = 0; i < 8; ++i) {
                float4 xv = reinterpret_cast<const float4*>(xr)[i];
                float4 qv = reinterpret_cast<const float4*>(qr)[i];
                float df0 = qv.x - xv.x, df1 = qv.y - xv.y;
                float df2 = qv.z - xv.z, df3 = qv.w - xv.w;
                lsum = fmaf(df0, df0, lsum); lsum = fmaf(df1, df1, lsum);
                lsum = fmaf(df2, df2, lsum); lsum = fmaf(df3, df3, lsum);
                float4 o = {xv.x + df0, xv.y + df1, xv.z + df2, xv.w + df3};
                reinterpret_cast<float4*>(orow)[i] = o;
            }
            if (half == 0) out[(size_t)N_ROWS * DIM + row] = (float)idx;
        }
    }
    #pragma unroll
    for (int off = 32; off > 0; off >>= 1) lsum += __shfl_down(lsum, off, 64);
    if (lane == 0) atomicAdd(loss, lsum);
}

// full np-exact rescan, only for triple-tie rows (rare)
__global__ void vq_fixup(const float* __restrict__ x, const float* __restrict__ emb,
                         const float* __restrict__ esq,
                         const unsigned int* __restrict__ cnt,
                         const unsigned int* __restrict__ list,
                         float* __restrict__ out, float* __restrict__ loss) {
#pragma clang fp contract(off)
    const int lane = threadIdx.x & 63;
    const int wid = (blockIdx.x * blockDim.x + threadIdx.x) >> 6;
    const int nw = (256 * 256) >> 6;
    unsigned count = *cnt;
    if (count > LIST_CAP) count = LIST_CAP;
    for (unsigned i = wid; i < count; i += nw) {
        const int row = (int)list[i];
        float xv[DIM];
        const float4* xp = reinterpret_cast<const float4*>(x + (size_t)row * DIM);
        #pragma unroll
        for (int q = 0; q < 16; ++q) {
            float4 v = xp[q];
            xv[4*q+0] = v.x; xv[4*q+1] = v.y; xv[4*q+2] = v.z; xv[4*q+3] = v.w;
        }
        float xsq = np_sq64(xv);
        float best = INFINITY; int bidx = 0x7fffffff;
        for (int t = 0; t < K_CODES / 64; ++t) {
            const int k = lane + t * 64;   // ascending per lane
            float dot = np_dot64(xv, emb + (size_t)k * DIM);
            float tt = xsq + esq[k];
            float dist = tt - 2.0f * dot;
            if (dist < best) { best = dist; bidx = k; }
        }
        #pragma unroll
        for (int m = 1; m < 64; m <<= 1) {   // lexicographic (dist, idx) min
            float ob = __shfl_xor(best, m, 64);
            int   oi = __shfl_xor(bidx, m, 64);
            if (ob < best || (ob == best && oi < bidx)) { best = ob; bidx = oi; }
        }
        const float xd = x[(size_t)row * DIM + lane];
        const float qd = emb[(size_t)bidx * DIM + lane];
        const float df = qd - xd;
        out[(size_t)row * DIM + lane] = xd + df;
        if (lane == 0) out[(size_t)N_ROWS * DIM + row] = (float)bidx;
        float l2 = df * df;
        #pragma unroll
        for (int off = 32; off > 0; off >>= 1) l2 += __shfl_down(l2, off, 64);
        if (lane == 0) atomicAdd(loss, l2);
    }
}

__global__ void vq_final(const float* __restrict__ loss_acc, float* __restrict__ out_loss) {
    if (threadIdx.x == 0 && blockIdx.x == 0)
        out_loss[0] = loss_acc[0] / (float)((size_t)N_ROWS * DIM);
}

extern "C" void kernel_launch(void* const* d_in, const int* in_sizes, int n_in,
                              void* d_out, int out_size, void* d_ws, size_t ws_size,
                              hipStream_t stream) {
    const float* x   = (const float*)d_in[0];
    const float* emb = (const float*)d_in[1];
    float* out = (float*)d_out;

    unsigned int* cnt  = (unsigned int*)d_ws;
    float* loss        = (float*)d_ws + 1;
    float* esq         = (float*)d_ws + 4;
    unsigned short* wsB = (unsigned short*)((char*)d_ws + 8192);
    unsigned int* list = (unsigned int*)((char*)d_ws + 270336);

    vq_prep<<<dim3(16), dim3(256), 0, stream>>>(emb, esq, wsB, cnt, loss);
    vq_mfma<<<dim3(N_ROWS / 256), dim3(256), 0, stream>>>(x, emb, esq, wsB, out,
                                                          cnt, list, loss);
    vq_fixup<<<dim3(256), dim3(256), 0, stream>>>(x, emb, esq, cnt, list, out, loss);
    vq_final<<<dim3(1), dim3(1), 0, stream>>>(loss, out + (size_t)N_ROWS * DIM + N_ROWS);
}